// Round 1
// baseline (413.052 us; speedup 1.0000x reference)
//
#include <hip/hip_runtime.h>

#define N_NODES  50000
#define N_EDGES  800000
#define D_OUTF   128
#define F_PACK   256          // agg row: Xh(128) | eps counts (128), bf16
#define NTILES   3125         // 50000 / 16, exact
#define GEMM_BLOCKS 512
#define NB1      196          // ceil(50000/256) scan blocks
// merged pack kernel block ranges
#define PBX 6250              // pack_xh fp8: 50000*32 threads (exact)
#define PBB 25000             // pack_bits + eps passthrough: 6.4M threads (exact)
#define PBZ 196               // zero cnt
#define PBW 80                // W fragment pre-pack: 20480 threads (exact)
#define PB_TOT (PBX + PBB + PBZ + PBW + 1)   // +1 block zeroes done counters

#define OUTB_F4  6400000      // broadcast region float4 count (exact: 25000 blocks)
#define EPS_OFF  25600000L    // float offset of eps passthrough region in out
#define INV_N    (1.0f / (float)N_NODES)

typedef __attribute__((ext_vector_type(8))) short bf16x8;
typedef __attribute__((ext_vector_type(4))) float f32x4;
typedef __attribute__((ext_vector_type(2))) float f32x2;

__device__ __forceinline__ unsigned short f2bf(float x) {
  unsigned int u = __float_as_uint(x);
  u += 0x7FFFu + ((u >> 16) & 1u);           // RNE
  return (unsigned short)(u >> 16);
}
__device__ __forceinline__ unsigned int pack2(float a, float b) {
  return (unsigned int)f2bf(a) | ((unsigned int)f2bf(b) << 16);
}
// byte-spread popcount helpers: rep = byte B replicated 4x.
__device__ __forceinline__ unsigned int spreadLo(unsigned int rep) {
  return (((rep & 0x08040201u) + 0x7F7F7F7Fu) >> 7) & 0x01010101u;
}
__device__ __forceinline__ unsigned int spreadHi(unsigned int rep) {
  return (((rep & 0x80402010u) + 0x7F7F7F7Fu) >> 7) & 0x01010101u;
}
// accumulate 4 fp8 (one dword) into 4 fp32 accumulators
__device__ __forceinline__ void f8acc(unsigned int w, float& a0, float& a1,
                                      float& a2, float& a3) {
  f32x2 p0 = __builtin_amdgcn_cvt_pk_f32_fp8(w, false);  // bytes 0,1
  f32x2 p1 = __builtin_amdgcn_cvt_pk_f32_fp8(w, true);   // bytes 2,3
  a0 += p0.x; a1 += p0.y; a2 += p1.x; a3 += p1.y;
}

// ---- merged prep: X|h -> fp8 e4m3, eps -> bitmask + out-passthrough,
//      zero cnt, pre-pack W fragments, zero done counters ------------------
__global__ void k_pack(const float* __restrict__ X, const float* __restrict__ h,
                       const float* __restrict__ eps, const float* __restrict__ W,
                       unsigned int* __restrict__ featF8,
                       unsigned int* __restrict__ epsb, int* __restrict__ cnt,
                       unsigned short* __restrict__ Wp,
                       float* __restrict__ outEps, int* __restrict__ done) {
  int blk = blockIdx.x, tid = threadIdx.x;
  if (blk < PBX) {
    int t = blk * 256 + tid;                 // < 1.6M exact (node, feature-quad)
    int node = t >> 5, f = (t & 31) << 2;    // X/h boundary at 96 (mult of 4)
    float a0, a1, a2, a3;
    if (f < 96) {
      const float* p = X + node * 96 + f;
      a0 = p[0]; a1 = p[1]; a2 = p[2]; a3 = p[3];
    } else {
      const float* p = h + node * 32 + (f - 96);
      a0 = p[0]; a1 = p[1]; a2 = p[2]; a3 = p[3];
    }
    unsigned int d = __builtin_amdgcn_cvt_pk_fp8_f32(a0, a1, 0, false);
    d = __builtin_amdgcn_cvt_pk_fp8_f32(a2, a3, d, true);
    featF8[t] = d;                           // feature f' at byte f'%4 of dword f'/4
  } else if (blk < PBX + PBB) {
    long g = (long)(blk - PBX) * 256 + tid;  // < 6.4M exact
    float v = eps[g];
    outEps[g] = v;                           // eps passthrough written here (saves
                                             // a second 25.6MB read in k_out)
    unsigned long long m = __ballot(v > 0.5f);
    int lane = tid & 63;
    if ((lane & 31) == 0) {
      long idx = g >> 5;                     // = s*N + node
      int s = (int)(idx / N_NODES);
      int node = (int)(idx - (long)s * N_NODES);
      epsb[node * 4 + s] = (unsigned int)(m >> ((lane >> 5) * 32));
    }
  } else if (blk < PBX + PBB + PBZ) {
    int i = (blk - PBX - PBB) * 256 + tid;
    if (i < N_NODES) cnt[i] = 0;
  } else if (blk < PBX + PBB + PBZ + PBW) {
    // W fragment pre-pack: layout ((((i2*5+kb5)*4+quad)*16+col)*8+j) bf16,
    // i2 = output col-tile (8), kb5 = 4 Xh k-blocks + 1 eps k-block.
    int t = (blk - (PBX + PBB + PBZ)) * 256 + tid;   // < 20480 exact
    int j = t & 7, col = (t >> 3) & 15, quad = (t >> 7) & 3, r = t >> 9;
    int kb5 = r % 5, i2 = r / 5;
    int wr;
    if (kb5 < 4) {
      int k = kb5 * 32 + quad * 8 + j;
      wr = (k < 96) ? k : k + 32;            // h block at W rows 128..159
    } else {
      wr = 96 + quad * 8 + j;                // eps block at W rows 96..127
    }
    Wp[t] = f2bf(W[wr * D_OUTF + i2 * 16 + col]);
  } else {
    if (tid < 2) done[tid] = 0;              // done[0]=scan, done[1]=gemm
  }
}

// ---- CSR build -------------------------------------------------------------
__global__ void k_hist(const int* __restrict__ dst, int* __restrict__ cnt) {
  int i = blockIdx.x * blockDim.x + threadIdx.x;
  if (i < N_EDGES) atomicAdd(&cnt[dst[i]], 1);
}

// scan1: excl[i] = block-LOCAL exclusive prefix; bsum[blk] = block total.
// Fused scan2 via last-block-done: the final block to arrive scans the 196
// block totals into boff (release store of bsum + acq_rel counter + acquire
// loads; no spin -> deadlock-free).
__global__ void k_scan1(const int* __restrict__ cnt, int* __restrict__ excl,
                        int* __restrict__ bsum, int* __restrict__ boff,
                        int* __restrict__ done) {
  __shared__ int wpart[4];
  __shared__ int sd[256];
  __shared__ int lastf;
  int tid = threadIdx.x, lane = tid & 63, wid = tid >> 6;
  int i = blockIdx.x * 256 + tid;
  int v = (i < N_NODES) ? cnt[i] : 0;
  int x = v;
#pragma unroll
  for (int d = 1; d < 64; d <<= 1) {
    int t = __shfl_up(x, d, 64);
    if (lane >= d) x += t;
  }
  if (lane == 63) wpart[wid] = x;
  __syncthreads();
  if (tid == 0) {
    int s = 0;
#pragma unroll
    for (int w = 0; w < 4; ++w) { int t = wpart[w]; wpart[w] = s; s += t; }
    __hip_atomic_store(&bsum[blockIdx.x], s, __ATOMIC_RELEASE,
                       __HIP_MEMORY_SCOPE_AGENT);
    int d = __hip_atomic_fetch_add(done, 1, __ATOMIC_ACQ_REL,
                                   __HIP_MEMORY_SCOPE_AGENT);
    lastf = (d == NB1 - 1);
  }
  __syncthreads();
  if (i < N_NODES) excl[i] = wpart[wid] + x - v;
  if (lastf) {                               // block-uniform branch
    int bv = (tid < NB1)
                 ? __hip_atomic_load(&bsum[tid], __ATOMIC_ACQUIRE,
                                     __HIP_MEMORY_SCOPE_AGENT)
                 : 0;
    sd[tid] = bv;
    __syncthreads();
    for (int d = 1; d < 256; d <<= 1) {
      int t = (tid >= d) ? sd[tid - d] : 0;
      __syncthreads();
      sd[tid] += t;
      __syncthreads();
    }
    if (tid < NB1) boff[tid] = sd[tid] - bv;
  }
}

// scatter: global slot = excl[d] + boff[d>>8] + (cnt[d]-- - 1). cnt holds the
// degree from k_hist and is consumed as a descending cursor (neighbor order is
// an arbitrary permutation -> only fp32 reassociation noise downstream).
__global__ void k_scatter(const int* __restrict__ src, const int* __restrict__ dst,
                          const int* __restrict__ excl, const int* __restrict__ boff,
                          int* __restrict__ cnt, int* __restrict__ csr) {
  int i = blockIdx.x * blockDim.x + threadIdx.x;
  if (i < N_EDGES) {
    int d = dst[i];
    int r = atomicAdd(&cnt[d], -1);          // deg .. 1
    csr[excl[d] + boff[d >> 8] + r - 1] = src[i];
  }
}

// ---- aggregation: WAVE per node, 4 edge-slots x 16 feature-lanes, fp8 ------
__global__ __launch_bounds__(256) void k_agg_ep(
    const uint2* __restrict__ feat2, const unsigned int* __restrict__ epsw,
    const float* __restrict__ geps_p, const int* __restrict__ excl,
    const int* __restrict__ boff, const int* __restrict__ csr,
    uint4* __restrict__ agg4) {
  int wave = (blockIdx.x * blockDim.x + threadIdx.x) >> 6;   // node; grid exact
  int lane = threadIdx.x & 63;
  int li = lane & 15, es = lane >> 4;
  if (wave >= N_NODES) return;
  int n = wave;
  float ge = 1.0f + geps_p[0];
  int wsel = li >> 2, bsh = (li & 3) * 8;

  int off_n = excl[n] + boff[n >> 8];
  int e1 = (n == N_NODES - 1) ? N_EDGES : excl[n + 1] + boff[(n + 1) >> 8];

  // prefetch self row (used after reduction by lanes 0..15)
  uint2 sf = feat2[n * 16 + li];
  unsigned int swd = epsw[n * 4 + wsel];

  float af0 = 0.f, af1 = 0.f, af2 = 0.f, af3 = 0.f;
  float af4 = 0.f, af5 = 0.f, af6 = 0.f, af7 = 0.f;
  unsigned int accLo = 0, accHi = 0;

  int e = off_n + es;
  for (; e + 4 < e1; e += 8) {               // slots stride 4, unroll 2
    int s0 = csr[e], s1 = csr[e + 4];
    uint2 f0 = feat2[s0 * 16 + li];
    uint2 f1 = feat2[s1 * 16 + li];
    unsigned int w0 = epsw[s0 * 4 + wsel];
    unsigned int w1 = epsw[s1 * 4 + wsel];
    f8acc(f0.x, af0, af1, af2, af3);  f8acc(f0.y, af4, af5, af6, af7);
    f8acc(f1.x, af0, af1, af2, af3);  f8acc(f1.y, af4, af5, af6, af7);
    unsigned int B0 = (w0 >> bsh) & 0xFFu;
    unsigned int B1 = (w1 >> bsh) & 0xFFu;
    unsigned int r0 = B0 | (B0 << 8);  r0 |= r0 << 16;
    unsigned int r1 = B1 | (B1 << 8);  r1 |= r1 << 16;
    accLo += spreadLo(r0) + spreadLo(r1);
    accHi += spreadHi(r0) + spreadHi(r1);
  }
  if (e < e1) {
    int s0 = csr[e];
    uint2 f0 = feat2[s0 * 16 + li];
    unsigned int w0 = epsw[s0 * 4 + wsel];
    f8acc(f0.x, af0, af1, af2, af3);  f8acc(f0.y, af4, af5, af6, af7);
    unsigned int B0 = (w0 >> bsh) & 0xFFu;
    unsigned int r0 = B0 | (B0 << 8);  r0 |= r0 << 16;
    accLo += spreadLo(r0);
    accHi += spreadHi(r0);
  }

  // cross-slot reduction (lanes differing in bits 4,5). Packed-byte adds are
  // overflow-safe: per-byte totals <= degree << 255.
#pragma unroll
  for (int d = 16; d < 64; d <<= 1) {
    af0 += __shfl_xor(af0, d, 64);  af1 += __shfl_xor(af1, d, 64);
    af2 += __shfl_xor(af2, d, 64);  af3 += __shfl_xor(af3, d, 64);
    af4 += __shfl_xor(af4, d, 64);  af5 += __shfl_xor(af5, d, 64);
    af6 += __shfl_xor(af6, d, 64);  af7 += __shfl_xor(af7, d, 64);
    accLo += __shfl_xor((int)accLo, d, 64);
    accHi += __shfl_xor((int)accHi, d, 64);
  }

  if (es == 0) {
    // self term (fp8-rounded features, weight ge)
    f32x2 s0 = __builtin_amdgcn_cvt_pk_f32_fp8(sf.x, false);
    f32x2 s1 = __builtin_amdgcn_cvt_pk_f32_fp8(sf.x, true);
    f32x2 s2 = __builtin_amdgcn_cvt_pk_f32_fp8(sf.y, false);
    f32x2 s3 = __builtin_amdgcn_cvt_pk_f32_fp8(sf.y, true);
    af0 += ge * s0.x;  af1 += ge * s0.y;
    af2 += ge * s1.x;  af3 += ge * s1.y;
    af4 += ge * s2.x;  af5 += ge * s2.y;
    af6 += ge * s3.x;  af7 += ge * s3.y;
    unsigned int Bself = (swd >> bsh) & 0xFFu;
    float ev0 = ge * (float)(Bself & 1u)        + (float)(accLo & 0xFFu);
    float ev1 = ge * (float)((Bself >> 1) & 1u) + (float)((accLo >> 8) & 0xFFu);
    float ev2 = ge * (float)((Bself >> 2) & 1u) + (float)((accLo >> 16) & 0xFFu);
    float ev3 = ge * (float)((Bself >> 3) & 1u) + (float)((accLo >> 24) & 0xFFu);
    float ev4 = ge * (float)((Bself >> 4) & 1u) + (float)(accHi & 0xFFu);
    float ev5 = ge * (float)((Bself >> 5) & 1u) + (float)((accHi >> 8) & 0xFFu);
    float ev6 = ge * (float)((Bself >> 6) & 1u) + (float)((accHi >> 16) & 0xFFu);
    float ev7 = ge * (float)((Bself >> 7) & 1u) + (float)((accHi >> 24) & 0xFFu);

    uint4 oXh, oEp;
    oXh.x = pack2(af0, af1); oXh.y = pack2(af2, af3);
    oXh.z = pack2(af4, af5); oXh.w = pack2(af6, af7);
    oEp.x = pack2(ev0, ev1); oEp.y = pack2(ev2, ev3);
    oEp.z = pack2(ev4, ev5); oEp.w = pack2(ev6, ev7);
    agg4[n * 32 + li]      = oXh;   // features 8li..8li+7
    agg4[n * 32 + 16 + li] = oEp;   // eps features 128+8li..+7
  }
}

// ---- MFMA GEMM + bias + ReLU + node-sum -> per-block partials; the LAST
//      block to finish reduces partials into sums[512] (no atomic contention,
//      no extra dispatch). W fragments come pre-packed from k_pack. ---------
__global__ __launch_bounds__(256) void k_gemm(const unsigned short* __restrict__ agg,
    const unsigned short* __restrict__ Wp, const float* __restrict__ b,
    float* __restrict__ partial, float* __restrict__ sums,
    int* __restrict__ done2) {
  __shared__ int lastf;
  int tid = threadIdx.x;
  int lane = tid & 63;
  int w = tid >> 6;          // wave -> n-tiles {2w, 2w+1}
  int col = lane & 15;
  int quad = lane >> 4;

  const bf16x8* wp8 = (const bf16x8*)Wp;
  bf16x8 Bsh[2][4];
  bf16x8 Bep[2];
  float bias[2];
#pragma unroll
  for (int i = 0; i < 2; ++i) {
    int i2 = 2 * w + i;
    bias[i] = b[i2 * 16 + col];
#pragma unroll
    for (int kb = 0; kb < 4; ++kb)
      Bsh[i][kb] = wp8[((i2 * 5 + kb) * 4 + quad) * 16 + col];
    Bep[i] = wp8[((i2 * 5 + 4) * 4 + quad) * 16 + col];
  }

  f32x4 psum[4][2];
#pragma unroll
  for (int s = 0; s < 4; ++s)
#pragma unroll
    for (int i = 0; i < 2; ++i) psum[s][i] = (f32x4){0.f, 0.f, 0.f, 0.f};

  for (int t = blockIdx.x; t < NTILES; t += gridDim.x) {
    const unsigned short* arow = agg + (long)(t * 16 + col) * F_PACK;
    bf16x8 Ash[4];
#pragma unroll
    for (int kb = 0; kb < 4; ++kb)
      Ash[kb] = *(const bf16x8*)(arow + kb * 32 + quad * 8);
    f32x4 csh[2];
    csh[0] = (f32x4){0.f, 0.f, 0.f, 0.f};
    csh[1] = (f32x4){0.f, 0.f, 0.f, 0.f};
#pragma unroll
    for (int kb = 0; kb < 4; ++kb) {
      csh[0] = __builtin_amdgcn_mfma_f32_16x16x32_bf16(Ash[kb], Bsh[0][kb], csh[0], 0, 0, 0);
      csh[1] = __builtin_amdgcn_mfma_f32_16x16x32_bf16(Ash[kb], Bsh[1][kb], csh[1], 0, 0, 0);
    }
#pragma unroll
    for (int s = 0; s < 4; ++s) {
      bf16x8 Aep = *(const bf16x8*)(arow + 128 + s * 32 + quad * 8);
#pragma unroll
      for (int i = 0; i < 2; ++i) {
        f32x4 c = __builtin_amdgcn_mfma_f32_16x16x32_bf16(Aep, Bep[i], csh[i], 0, 0, 0);
#pragma unroll
        for (int r = 0; r < 4; ++r)
          psum[s][i][r] += fmaxf(c[r] + bias[i], 0.f);
      }
    }
  }

#pragma unroll
  for (int s = 0; s < 4; ++s)
#pragma unroll
    for (int i = 0; i < 2; ++i) {
      float v = psum[s][i][0] + psum[s][i][1] + psum[s][i][2] + psum[s][i][3];
      v += __shfl_xor(v, 16, 64);
      v += __shfl_xor(v, 32, 64);
      if (quad == 0)
        partial[blockIdx.x * 512 + s * 128 + (2 * w + i) * 16 + col] = v;
    }

  __threadfence();                            // partials -> device scope
  __syncthreads();
  if (tid == 0) {
    int d = __hip_atomic_fetch_add(done2, 1, __ATOMIC_ACQ_REL,
                                   __HIP_MEMORY_SCOPE_AGENT);
    lastf = (d == GEMM_BLOCKS - 1);
  }
  __syncthreads();
  if (lastf) {                                // acquire above invalidated L1
    float a0 = 0.f, a1 = 0.f;
#pragma unroll 4
    for (int bb = 0; bb < GEMM_BLOCKS; ++bb) {
      a0 += partial[(bb << 9) + tid];
      a1 += partial[(bb << 9) + tid + 256];
    }
    sums[tid] = a0;
    sums[tid + 256] = a1;
  }
}

// ---- broadcast output (mean+relu inline); eps already written by k_pack ----
__global__ void k_out(const float* __restrict__ sums, float* __restrict__ out) {
  int i = blockIdx.x * 256 + threadIdx.x;     // < 6.4M exact
  int o4 = i & 31;
  unsigned int sn = (unsigned int)i >> 5;     // s*N + node, < 200000
  unsigned int s = sn / (unsigned int)N_NODES;  // constant divisor -> magic mul
  float4 sv = ((const float4*)sums)[s * 32 + o4];
  float4 ov;
  ov.x = fmaxf(sv.x * INV_N, 0.f);
  ov.y = fmaxf(sv.y * INV_N, 0.f);
  ov.z = fmaxf(sv.z * INV_N, 0.f);
  ov.w = fmaxf(sv.w * INV_N, 0.f);
  ((float4*)out)[i] = ov;
}

extern "C" void kernel_launch(void* const* d_in, const int* in_sizes, int n_in,
                              void* d_out, int out_size, void* d_ws, size_t ws_size,
                              hipStream_t stream) {
  const float* X    = (const float*)d_in[0];
  const float* h    = (const float*)d_in[1];
  const float* eps  = (const float*)d_in[2];
  const float* W    = (const float*)d_in[3];
  const float* b    = (const float*)d_in[4];
  const float* geps = (const float*)d_in[5];
  const int*   src  = (const int*)d_in[6];
  const int*   dst  = (const int*)d_in[7];
  float* out = (float*)d_out;

  char* w = (char*)d_ws;
  unsigned int*  featF8 = (unsigned int*)w;  w += (size_t)N_NODES * 32 * 4;   // 6.4 MB
  unsigned int*  epsb   = (unsigned int*)w;  w += (size_t)N_NODES * 4 * 4;    // 0.8 MB
  unsigned int*  agg_u  = (unsigned int*)w;  w += (size_t)N_NODES * 128 * 4;  // 25.6 MB
  int*   excl     = (int*)w;   w += (size_t)(N_NODES + 16) * 4;
  int*   cnt      = (int*)w;   w += (size_t)N_NODES * 4;
  int*   csr      = (int*)w;   w += (size_t)N_EDGES * 4;
  int*   bsum     = (int*)w;   w += 256 * 4;
  int*   boff     = (int*)w;   w += 256 * 4;
  float* partial  = (float*)w; w += (size_t)GEMM_BLOCKS * 512 * 4;            // 1 MB
  unsigned short* Wp = (unsigned short*)w; w += (size_t)20480 * 2;            // 40 KB
  float* sums     = (float*)w; w += 512 * 4;
  int*   done     = (int*)w;   w += 64;

  int eb = (N_EDGES + 255) / 256;
  k_pack<<<PB_TOT, 256, 0, stream>>>(X, h, eps, W, featF8, epsb, cnt, Wp,
                                     out + EPS_OFF, done);
  k_hist<<<eb, 256, 0, stream>>>(dst, cnt);
  k_scan1<<<NB1, 256, 0, stream>>>(cnt, excl, bsum, boff, &done[0]);
  k_scatter<<<eb, 256, 0, stream>>>(src, dst, excl, boff, cnt, csr);

  k_agg_ep<<<(N_NODES * 64) / 256, 256, 0, stream>>>((const uint2*)featF8, epsb,
                                                     geps, excl, boff, csr,
                                                     (uint4*)agg_u);

  k_gemm<<<GEMM_BLOCKS, 256, 0, stream>>>((const unsigned short*)agg_u, Wp, b,
                                          partial, sums, &done[1]);

  k_out<<<OUTB_F4 / 256, 256, 0, stream>>>(sums, out);
}

// Round 2
// 331.693 us; speedup vs baseline: 1.2453x; 1.2453x over previous
//
#include <hip/hip_runtime.h>

#define N_NODES  50000
#define N_EDGES  800000
#define D_OUTF   128
#define F_PACK   256          // agg row: Xh(128) | eps counts (128), bf16
#define NTILES   3125         // 50000 / 16, exact
#define GEMM_BLOCKS 512
#define NB1      196          // ceil(50000/256) scan blocks
// merged pack kernel block ranges
#define PBX 6250              // pack_xh fp8: 50000*32 threads (exact)
#define PBB 25000             // pack_bits + eps passthrough: 6.4M threads (exact)
#define PBZ 196               // zero cnt
#define PBW 80                // W fragment pre-pack: 20480 threads (exact)
#define PB_TOT (PBX + PBB + PBZ + PBW + 1)   // +1 block zeroes sums + done

#define OUTB_F4  6400000      // broadcast region float4 count (exact: 25000 blocks)
#define EPS_OFF  25600000L    // float offset of eps passthrough region in out
#define INV_N    (1.0f / (float)N_NODES)

typedef __attribute__((ext_vector_type(8))) short bf16x8;
typedef __attribute__((ext_vector_type(4))) float f32x4;
typedef __attribute__((ext_vector_type(2))) float f32x2;

__device__ __forceinline__ unsigned short f2bf(float x) {
  unsigned int u = __float_as_uint(x);
  u += 0x7FFFu + ((u >> 16) & 1u);           // RNE
  return (unsigned short)(u >> 16);
}
__device__ __forceinline__ unsigned int pack2(float a, float b) {
  return (unsigned int)f2bf(a) | ((unsigned int)f2bf(b) << 16);
}
// byte-spread popcount helpers: rep = byte B replicated 4x.
__device__ __forceinline__ unsigned int spreadLo(unsigned int rep) {
  return (((rep & 0x08040201u) + 0x7F7F7F7Fu) >> 7) & 0x01010101u;
}
__device__ __forceinline__ unsigned int spreadHi(unsigned int rep) {
  return (((rep & 0x80402010u) + 0x7F7F7F7Fu) >> 7) & 0x01010101u;
}
// accumulate 4 fp8 (one dword) into 4 fp32 accumulators
__device__ __forceinline__ void f8acc(unsigned int w, float& a0, float& a1,
                                      float& a2, float& a3) {
  f32x2 p0 = __builtin_amdgcn_cvt_pk_f32_fp8(w, false);  // bytes 0,1
  f32x2 p1 = __builtin_amdgcn_cvt_pk_f32_fp8(w, true);   // bytes 2,3
  a0 += p0.x; a1 += p0.y; a2 += p1.x; a3 += p1.y;
}

// ---- merged prep: X|h -> fp8 e4m3, eps -> bitmask + out-passthrough,
//      zero cnt, pre-pack W fragments, zero sums & done --------------------
__global__ void k_pack(const float* __restrict__ X, const float* __restrict__ h,
                       const float* __restrict__ eps, const float* __restrict__ W,
                       unsigned int* __restrict__ featF8,
                       unsigned int* __restrict__ epsb, int* __restrict__ cnt,
                       unsigned short* __restrict__ Wp,
                       float* __restrict__ outEps, float* __restrict__ sums,
                       int* __restrict__ done) {
  int blk = blockIdx.x, tid = threadIdx.x;
  if (blk < PBX) {
    int t = blk * 256 + tid;                 // < 1.6M exact (node, feature-quad)
    int node = t >> 5, f = (t & 31) << 2;    // X/h boundary at 96 (mult of 4)
    float a0, a1, a2, a3;
    if (f < 96) {
      const float* p = X + node * 96 + f;
      a0 = p[0]; a1 = p[1]; a2 = p[2]; a3 = p[3];
    } else {
      const float* p = h + node * 32 + (f - 96);
      a0 = p[0]; a1 = p[1]; a2 = p[2]; a3 = p[3];
    }
    unsigned int d = __builtin_amdgcn_cvt_pk_fp8_f32(a0, a1, 0, false);
    d = __builtin_amdgcn_cvt_pk_fp8_f32(a2, a3, d, true);
    featF8[t] = d;                           // feature f' at byte f'%4 of dword f'/4
  } else if (blk < PBX + PBB) {
    long g = (long)(blk - PBX) * 256 + tid;  // < 6.4M exact
    float v = eps[g];
    outEps[g] = v;                           // eps passthrough written here (saves
                                             // a second 25.6MB read in k_out)
    unsigned long long m = __ballot(v > 0.5f);
    int lane = tid & 63;
    if ((lane & 31) == 0) {
      long idx = g >> 5;                     // = s*N + node
      int s = (int)(idx / N_NODES);
      int node = (int)(idx - (long)s * N_NODES);
      epsb[node * 4 + s] = (unsigned int)(m >> ((lane >> 5) * 32));
    }
  } else if (blk < PBX + PBB + PBZ) {
    int i = (blk - PBX - PBB) * 256 + tid;
    if (i < N_NODES) cnt[i] = 0;
  } else if (blk < PBX + PBB + PBZ + PBW) {
    // W fragment pre-pack: layout ((((i2*5+kb5)*4+quad)*16+col)*8+j) bf16,
    // i2 = output col-tile (8), kb5 = 4 Xh k-blocks + 1 eps k-block.
    int t = (blk - (PBX + PBB + PBZ)) * 256 + tid;   // < 20480 exact
    int j = t & 7, col = (t >> 3) & 15, quad = (t >> 7) & 3, r = t >> 9;
    int kb5 = r % 5, i2 = r / 5;
    int wr;
    if (kb5 < 4) {
      int k = kb5 * 32 + quad * 8 + j;
      wr = (k < 96) ? k : k + 32;            // h block at W rows 128..159
    } else {
      wr = 96 + quad * 8 + j;                // eps block at W rows 96..127
    }
    Wp[t] = f2bf(W[wr * D_OUTF + i2 * 16 + col]);
  } else {
    sums[tid] = 0.f;                         // zeroed for k_gemm atomics
    sums[tid + 256] = 0.f;
    if (tid < 2) done[tid] = 0;              // done[0]=scan counter
  }
}

// ---- CSR build -------------------------------------------------------------
__global__ void k_hist(const int* __restrict__ dst, int* __restrict__ cnt) {
  int i = blockIdx.x * blockDim.x + threadIdx.x;
  if (i < N_EDGES) atomicAdd(&cnt[dst[i]], 1);
}

// scan1: excl[i] = block-LOCAL exclusive prefix; bsum[blk] = block total.
// Fused scan2 via last-block-done: the final block to arrive scans the 196
// block totals into boff (release store of bsum + acq_rel counter + acquire
// loads; no spin -> deadlock-free).
__global__ void k_scan1(const int* __restrict__ cnt, int* __restrict__ excl,
                        int* __restrict__ bsum, int* __restrict__ boff,
                        int* __restrict__ done) {
  __shared__ int wpart[4];
  __shared__ int sd[256];
  __shared__ int lastf;
  int tid = threadIdx.x, lane = tid & 63, wid = tid >> 6;
  int i = blockIdx.x * 256 + tid;
  int v = (i < N_NODES) ? cnt[i] : 0;
  int x = v;
#pragma unroll
  for (int d = 1; d < 64; d <<= 1) {
    int t = __shfl_up(x, d, 64);
    if (lane >= d) x += t;
  }
  if (lane == 63) wpart[wid] = x;
  __syncthreads();
  if (tid == 0) {
    int s = 0;
#pragma unroll
    for (int w = 0; w < 4; ++w) { int t = wpart[w]; wpart[w] = s; s += t; }
    __hip_atomic_store(&bsum[blockIdx.x], s, __ATOMIC_RELEASE,
                       __HIP_MEMORY_SCOPE_AGENT);
    int d = __hip_atomic_fetch_add(done, 1, __ATOMIC_ACQ_REL,
                                   __HIP_MEMORY_SCOPE_AGENT);
    lastf = (d == NB1 - 1);
  }
  __syncthreads();
  if (i < N_NODES) excl[i] = wpart[wid] + x - v;
  if (lastf) {                               // block-uniform branch
    int bv = (tid < NB1)
                 ? __hip_atomic_load(&bsum[tid], __ATOMIC_ACQUIRE,
                                     __HIP_MEMORY_SCOPE_AGENT)
                 : 0;
    sd[tid] = bv;
    __syncthreads();
    for (int d = 1; d < 256; d <<= 1) {
      int t = (tid >= d) ? sd[tid - d] : 0;
      __syncthreads();
      sd[tid] += t;
      __syncthreads();
    }
    if (tid < NB1) boff[tid] = sd[tid] - bv;
  }
}

// scatter: global slot = excl[d] + boff[d>>8] + (cnt[d]-- - 1). cnt holds the
// degree from k_hist and is consumed as a descending cursor (neighbor order is
// an arbitrary permutation -> only fp32 reassociation noise downstream).
__global__ void k_scatter(const int* __restrict__ src, const int* __restrict__ dst,
                          const int* __restrict__ excl, const int* __restrict__ boff,
                          int* __restrict__ cnt, int* __restrict__ csr) {
  int i = blockIdx.x * blockDim.x + threadIdx.x;
  if (i < N_EDGES) {
    int d = dst[i];
    int r = atomicAdd(&cnt[d], -1);          // deg .. 1
    csr[excl[d] + boff[d >> 8] + r - 1] = src[i];
  }
}

// ---- aggregation: WAVE per node, 4 edge-slots x 16 feature-lanes, fp8 ------
__global__ __launch_bounds__(256) void k_agg_ep(
    const uint2* __restrict__ feat2, const unsigned int* __restrict__ epsw,
    const float* __restrict__ geps_p, const int* __restrict__ excl,
    const int* __restrict__ boff, const int* __restrict__ csr,
    uint4* __restrict__ agg4) {
  int wave = (blockIdx.x * blockDim.x + threadIdx.x) >> 6;   // node; grid exact
  int lane = threadIdx.x & 63;
  int li = lane & 15, es = lane >> 4;
  if (wave >= N_NODES) return;
  int n = wave;
  float ge = 1.0f + geps_p[0];
  int wsel = li >> 2, bsh = (li & 3) * 8;

  int off_n = excl[n] + boff[n >> 8];
  int e1 = (n == N_NODES - 1) ? N_EDGES : excl[n + 1] + boff[(n + 1) >> 8];

  // prefetch self row (used after reduction by lanes 0..15)
  uint2 sf = feat2[n * 16 + li];
  unsigned int swd = epsw[n * 4 + wsel];

  float af0 = 0.f, af1 = 0.f, af2 = 0.f, af3 = 0.f;
  float af4 = 0.f, af5 = 0.f, af6 = 0.f, af7 = 0.f;
  unsigned int accLo = 0, accHi = 0;

  int e = off_n + es;
  for (; e + 4 < e1; e += 8) {               // slots stride 4, unroll 2
    int s0 = csr[e], s1 = csr[e + 4];
    uint2 f0 = feat2[s0 * 16 + li];
    uint2 f1 = feat2[s1 * 16 + li];
    unsigned int w0 = epsw[s0 * 4 + wsel];
    unsigned int w1 = epsw[s1 * 4 + wsel];
    f8acc(f0.x, af0, af1, af2, af3);  f8acc(f0.y, af4, af5, af6, af7);
    f8acc(f1.x, af0, af1, af2, af3);  f8acc(f1.y, af4, af5, af6, af7);
    unsigned int B0 = (w0 >> bsh) & 0xFFu;
    unsigned int B1 = (w1 >> bsh) & 0xFFu;
    unsigned int r0 = B0 | (B0 << 8);  r0 |= r0 << 16;
    unsigned int r1 = B1 | (B1 << 8);  r1 |= r1 << 16;
    accLo += spreadLo(r0) + spreadLo(r1);
    accHi += spreadHi(r0) + spreadHi(r1);
  }
  if (e < e1) {
    int s0 = csr[e];
    uint2 f0 = feat2[s0 * 16 + li];
    unsigned int w0 = epsw[s0 * 4 + wsel];
    f8acc(f0.x, af0, af1, af2, af3);  f8acc(f0.y, af4, af5, af6, af7);
    unsigned int B0 = (w0 >> bsh) & 0xFFu;
    unsigned int r0 = B0 | (B0 << 8);  r0 |= r0 << 16;
    accLo += spreadLo(r0);
    accHi += spreadHi(r0);
  }

  // cross-slot reduction (lanes differing in bits 4,5). Packed-byte adds are
  // overflow-safe: per-byte totals <= degree << 255.
#pragma unroll
  for (int d = 16; d < 64; d <<= 1) {
    af0 += __shfl_xor(af0, d, 64);  af1 += __shfl_xor(af1, d, 64);
    af2 += __shfl_xor(af2, d, 64);  af3 += __shfl_xor(af3, d, 64);
    af4 += __shfl_xor(af4, d, 64);  af5 += __shfl_xor(af5, d, 64);
    af6 += __shfl_xor(af6, d, 64);  af7 += __shfl_xor(af7, d, 64);
    accLo += __shfl_xor((int)accLo, d, 64);
    accHi += __shfl_xor((int)accHi, d, 64);
  }

  if (es == 0) {
    // self term (fp8-rounded features, weight ge)
    f32x2 s0 = __builtin_amdgcn_cvt_pk_f32_fp8(sf.x, false);
    f32x2 s1 = __builtin_amdgcn_cvt_pk_f32_fp8(sf.x, true);
    f32x2 s2 = __builtin_amdgcn_cvt_pk_f32_fp8(sf.y, false);
    f32x2 s3 = __builtin_amdgcn_cvt_pk_f32_fp8(sf.y, true);
    af0 += ge * s0.x;  af1 += ge * s0.y;
    af2 += ge * s1.x;  af3 += ge * s1.y;
    af4 += ge * s2.x;  af5 += ge * s2.y;
    af6 += ge * s3.x;  af7 += ge * s3.y;
    unsigned int Bself = (swd >> bsh) & 0xFFu;
    float ev0 = ge * (float)(Bself & 1u)        + (float)(accLo & 0xFFu);
    float ev1 = ge * (float)((Bself >> 1) & 1u) + (float)((accLo >> 8) & 0xFFu);
    float ev2 = ge * (float)((Bself >> 2) & 1u) + (float)((accLo >> 16) & 0xFFu);
    float ev3 = ge * (float)((Bself >> 3) & 1u) + (float)((accLo >> 24) & 0xFFu);
    float ev4 = ge * (float)((Bself >> 4) & 1u) + (float)(accHi & 0xFFu);
    float ev5 = ge * (float)((Bself >> 5) & 1u) + (float)((accHi >> 8) & 0xFFu);
    float ev6 = ge * (float)((Bself >> 6) & 1u) + (float)((accHi >> 16) & 0xFFu);
    float ev7 = ge * (float)((Bself >> 7) & 1u) + (float)((accHi >> 24) & 0xFFu);

    uint4 oXh, oEp;
    oXh.x = pack2(af0, af1); oXh.y = pack2(af2, af3);
    oXh.z = pack2(af4, af5); oXh.w = pack2(af6, af7);
    oEp.x = pack2(ev0, ev1); oEp.y = pack2(ev2, ev3);
    oEp.z = pack2(ev4, ev5); oEp.w = pack2(ev6, ev7);
    agg4[n * 32 + li]      = oXh;   // features 8li..8li+7
    agg4[n * 32 + 16 + li] = oEp;   // eps features 128+8li..+7
  }
}

// ---- MFMA GEMM + bias + ReLU + node-sum -> fire-and-forget atomicAdd into
//      sums[512]. 512 blocks x 512 distinct addresses; atomicAdd without
//      return value does not stall the wave (round-1's last-block-reduction
//      variant serialized a 1MB single-block tail: 108us at 1% util). ------
__global__ __launch_bounds__(256) void k_gemm(const unsigned short* __restrict__ agg,
    const unsigned short* __restrict__ Wp, const float* __restrict__ b,
    float* __restrict__ sums) {
  int tid = threadIdx.x;
  int lane = tid & 63;
  int w = tid >> 6;          // wave -> n-tiles {2w, 2w+1}
  int col = lane & 15;
  int quad = lane >> 4;

  const bf16x8* wp8 = (const bf16x8*)Wp;
  bf16x8 Bsh[2][4];
  bf16x8 Bep[2];
  float bias[2];
#pragma unroll
  for (int i = 0; i < 2; ++i) {
    int i2 = 2 * w + i;
    bias[i] = b[i2 * 16 + col];
#pragma unroll
    for (int kb = 0; kb < 4; ++kb)
      Bsh[i][kb] = wp8[((i2 * 5 + kb) * 4 + quad) * 16 + col];
    Bep[i] = wp8[((i2 * 5 + 4) * 4 + quad) * 16 + col];
  }

  f32x4 psum[4][2];
#pragma unroll
  for (int s = 0; s < 4; ++s)
#pragma unroll
    for (int i = 0; i < 2; ++i) psum[s][i] = (f32x4){0.f, 0.f, 0.f, 0.f};

  for (int t = blockIdx.x; t < NTILES; t += gridDim.x) {
    const unsigned short* arow = agg + (long)(t * 16 + col) * F_PACK;
    bf16x8 Ash[4];
#pragma unroll
    for (int kb = 0; kb < 4; ++kb)
      Ash[kb] = *(const bf16x8*)(arow + kb * 32 + quad * 8);
    f32x4 csh[2];
    csh[0] = (f32x4){0.f, 0.f, 0.f, 0.f};
    csh[1] = (f32x4){0.f, 0.f, 0.f, 0.f};
#pragma unroll
    for (int kb = 0; kb < 4; ++kb) {
      csh[0] = __builtin_amdgcn_mfma_f32_16x16x32_bf16(Ash[kb], Bsh[0][kb], csh[0], 0, 0, 0);
      csh[1] = __builtin_amdgcn_mfma_f32_16x16x32_bf16(Ash[kb], Bsh[1][kb], csh[1], 0, 0, 0);
    }
#pragma unroll
    for (int s = 0; s < 4; ++s) {
      bf16x8 Aep = *(const bf16x8*)(arow + 128 + s * 32 + quad * 8);
#pragma unroll
      for (int i = 0; i < 2; ++i) {
        f32x4 c = __builtin_amdgcn_mfma_f32_16x16x32_bf16(Aep, Bep[i], csh[i], 0, 0, 0);
#pragma unroll
        for (int r = 0; r < 4; ++r)
          psum[s][i][r] += fmaxf(c[r] + bias[i], 0.f);
      }
    }
  }

#pragma unroll
  for (int s = 0; s < 4; ++s)
#pragma unroll
    for (int i = 0; i < 2; ++i) {
      float v = psum[s][i][0] + psum[s][i][1] + psum[s][i][2] + psum[s][i][3];
      v += __shfl_xor(v, 16, 64);
      v += __shfl_xor(v, 32, 64);
      if (quad == 0)
        atomicAdd(&sums[s * 128 + (2 * w + i) * 16 + col], v);
    }
}

// ---- broadcast output (mean+relu inline); eps already written by k_pack ----
__global__ void k_out(const float* __restrict__ sums, float* __restrict__ out) {
  int i = blockIdx.x * 256 + threadIdx.x;     // < 6.4M exact
  int o4 = i & 31;
  unsigned int sn = (unsigned int)i >> 5;     // s*N + node, < 200000
  unsigned int s = sn / (unsigned int)N_NODES;  // constant divisor -> magic mul
  float4 sv = ((const float4*)sums)[s * 32 + o4];
  float4 ov;
  ov.x = fmaxf(sv.x * INV_N, 0.f);
  ov.y = fmaxf(sv.y * INV_N, 0.f);
  ov.z = fmaxf(sv.z * INV_N, 0.f);
  ov.w = fmaxf(sv.w * INV_N, 0.f);
  ((float4*)out)[i] = ov;
}

extern "C" void kernel_launch(void* const* d_in, const int* in_sizes, int n_in,
                              void* d_out, int out_size, void* d_ws, size_t ws_size,
                              hipStream_t stream) {
  const float* X    = (const float*)d_in[0];
  const float* h    = (const float*)d_in[1];
  const float* eps  = (const float*)d_in[2];
  const float* W    = (const float*)d_in[3];
  const float* b    = (const float*)d_in[4];
  const float* geps = (const float*)d_in[5];
  const int*   src  = (const int*)d_in[6];
  const int*   dst  = (const int*)d_in[7];
  float* out = (float*)d_out;

  char* w = (char*)d_ws;
  unsigned int*  featF8 = (unsigned int*)w;  w += (size_t)N_NODES * 32 * 4;   // 6.4 MB
  unsigned int*  epsb   = (unsigned int*)w;  w += (size_t)N_NODES * 4 * 4;    // 0.8 MB
  unsigned int*  agg_u  = (unsigned int*)w;  w += (size_t)N_NODES * 128 * 4;  // 25.6 MB
  int*   excl     = (int*)w;   w += (size_t)(N_NODES + 16) * 4;
  int*   cnt      = (int*)w;   w += (size_t)N_NODES * 4;
  int*   csr      = (int*)w;   w += (size_t)N_EDGES * 4;
  int*   bsum     = (int*)w;   w += 256 * 4;
  int*   boff     = (int*)w;   w += 256 * 4;
  unsigned short* Wp = (unsigned short*)w; w += (size_t)20480 * 2;            // 40 KB
  float* sums     = (float*)w; w += 512 * 4;
  int*   done     = (int*)w;   w += 64;

  int eb = (N_EDGES + 255) / 256;
  k_pack<<<PB_TOT, 256, 0, stream>>>(X, h, eps, W, featF8, epsb, cnt, Wp,
                                     out + EPS_OFF, sums, done);
  k_hist<<<eb, 256, 0, stream>>>(dst, cnt);
  k_scan1<<<NB1, 256, 0, stream>>>(cnt, excl, bsum, boff, &done[0]);
  k_scatter<<<eb, 256, 0, stream>>>(src, dst, excl, boff, cnt, csr);

  k_agg_ep<<<(N_NODES * 64) / 256, 256, 0, stream>>>((const uint2*)featF8, epsb,
                                                     geps, excl, boff, csr,
                                                     (uint4*)agg_u);

  k_gemm<<<GEMM_BLOCKS, 256, 0, stream>>>((const unsigned short*)agg_u, Wp, b,
                                          sums);

  k_out<<<OUTB_F4 / 256, 256, 0, stream>>>(sums, out);
}

// Round 3
// 318.649 us; speedup vs baseline: 1.2963x; 1.0409x over previous
//
#include <hip/hip_runtime.h>

#define N_NODES  50000
#define N_EDGES  800000
#define D_OUTF   128
#define F_PACK   256          // agg row: Xh(128) | eps counts (128), bf16
#define NTILES   3125         // 50000 / 16, exact
#define GEMM_BLOCKS 256
#define NB1      196          // ceil(50000/256) scan blocks
// merged pack kernel block ranges
#define PBX 6250              // pack_xh fp8: 50000*32 threads (exact)
#define PBB 25000             // pack_bits + eps passthrough: 6.4M threads (exact)
#define PBH 3125              // edge histogram: 800000 threads (exact)
#define PBW 80                // W fragment pre-pack: 20480 threads (exact)
#define PB_TOT (PBX + PBB + PBH + PBW + 1)   // +1 block zeroes sums + done

#define OUTB_F4  6400000      // broadcast region float4 count (exact: 25000 blocks)
#define EPS_OFF  25600000L    // float offset of eps passthrough region in out
#define INV_N    (1.0f / (float)N_NODES)

typedef __attribute__((ext_vector_type(8))) short bf16x8;
typedef __attribute__((ext_vector_type(4))) float f32x4;
typedef __attribute__((ext_vector_type(2))) float f32x2;

__device__ __forceinline__ unsigned short f2bf(float x) {
  unsigned int u = __float_as_uint(x);
  u += 0x7FFFu + ((u >> 16) & 1u);           // RNE
  return (unsigned short)(u >> 16);
}
__device__ __forceinline__ unsigned int pack2(float a, float b) {
  return (unsigned int)f2bf(a) | ((unsigned int)f2bf(b) << 16);
}
// byte-spread popcount helpers: rep = byte B replicated 4x.
__device__ __forceinline__ unsigned int spreadLo(unsigned int rep) {
  return (((rep & 0x08040201u) + 0x7F7F7F7Fu) >> 7) & 0x01010101u;
}
__device__ __forceinline__ unsigned int spreadHi(unsigned int rep) {
  return (((rep & 0x80402010u) + 0x7F7F7F7Fu) >> 7) & 0x01010101u;
}
// accumulate 4 fp8 (one dword) into 4 fp32 accumulators
__device__ __forceinline__ void f8acc(unsigned int w, float& a0, float& a1,
                                      float& a2, float& a3) {
  f32x2 p0 = __builtin_amdgcn_cvt_pk_f32_fp8(w, false);  // bytes 0,1
  f32x2 p1 = __builtin_amdgcn_cvt_pk_f32_fp8(w, true);   // bytes 2,3
  a0 += p0.x; a1 += p0.y; a2 += p1.x; a3 += p1.y;
}

// ---- merged prep: X|h -> fp8 e4m3, eps -> bitmask + out-passthrough,
//      edge histogram (cnt pre-zeroed by memsetAsync), W fragments, sums ----
__global__ void k_pack(const float* __restrict__ X, const float* __restrict__ h,
                       const float* __restrict__ eps, const float* __restrict__ W,
                       const int* __restrict__ dst,
                       unsigned int* __restrict__ featF8,
                       unsigned int* __restrict__ epsb, int* __restrict__ cnt,
                       unsigned short* __restrict__ Wp,
                       float* __restrict__ outEps, float* __restrict__ sums,
                       int* __restrict__ done) {
  int blk = blockIdx.x, tid = threadIdx.x;
  if (blk < PBX) {
    int t = blk * 256 + tid;                 // < 1.6M exact (node, feature-quad)
    int node = t >> 5, f = (t & 31) << 2;    // X/h boundary at 96 (mult of 4)
    float a0, a1, a2, a3;
    if (f < 96) {
      const float* p = X + node * 96 + f;
      a0 = p[0]; a1 = p[1]; a2 = p[2]; a3 = p[3];
    } else {
      const float* p = h + node * 32 + (f - 96);
      a0 = p[0]; a1 = p[1]; a2 = p[2]; a3 = p[3];
    }
    unsigned int d = __builtin_amdgcn_cvt_pk_fp8_f32(a0, a1, 0, false);
    d = __builtin_amdgcn_cvt_pk_fp8_f32(a2, a3, d, true);
    featF8[t] = d;                           // feature f' at byte f'%4 of dword f'/4
  } else if (blk < PBX + PBB) {
    long g = (long)(blk - PBX) * 256 + tid;  // < 6.4M exact
    float v = eps[g];
    outEps[g] = v;                           // eps passthrough written here (saves
                                             // a second 25.6MB read in k_out)
    unsigned long long m = __ballot(v > 0.5f);
    int lane = tid & 63;
    if ((lane & 31) == 0) {
      long idx = g >> 5;                     // = s*N + node
      int s = (int)(idx / N_NODES);
      int node = (int)(idx - (long)s * N_NODES);
      epsb[node * 4 + s] = (unsigned int)(m >> ((lane >> 5) * 32));
    }
  } else if (blk < PBX + PBB + PBH) {
    int i = (blk - PBX - PBB) * 256 + tid;   // < 800000 exact
    atomicAdd(&cnt[dst[i]], 1);              // hist overlapped with streaming
  } else if (blk < PBX + PBB + PBH + PBW) {
    // W fragment pre-pack: layout ((((i2*5+kb5)*4+quad)*16+col)*8+j) bf16,
    // i2 = output col-tile (8), kb5 = 4 Xh k-blocks + 1 eps k-block.
    int t = (blk - (PBX + PBB + PBH)) * 256 + tid;   // < 20480 exact
    int j = t & 7, col = (t >> 3) & 15, quad = (t >> 7) & 3, r = t >> 9;
    int kb5 = r % 5, i2 = r / 5;
    int wr;
    if (kb5 < 4) {
      int k = kb5 * 32 + quad * 8 + j;
      wr = (k < 96) ? k : k + 32;            // h block at W rows 128..159
    } else {
      wr = 96 + quad * 8 + j;                // eps block at W rows 96..127
    }
    Wp[t] = f2bf(W[wr * D_OUTF + i2 * 16 + col]);
  } else {
    sums[tid] = 0.f;                         // zeroed for k_gemm atomics
    sums[tid + 256] = 0.f;
    if (tid < 2) done[tid] = 0;              // done[0]=scan counter
  }
}

// scan1: excl[i] = block-LOCAL exclusive prefix; bsum[blk] = block total.
// Fused scan2 via last-block-done: the final block to arrive scans the 196
// block totals into boff (release store of bsum + acq_rel counter + acquire
// loads; no spin -> deadlock-free).
__global__ void k_scan1(const int* __restrict__ cnt, int* __restrict__ excl,
                        int* __restrict__ bsum, int* __restrict__ boff,
                        int* __restrict__ done) {
  __shared__ int wpart[4];
  __shared__ int sd[256];
  __shared__ int lastf;
  int tid = threadIdx.x, lane = tid & 63, wid = tid >> 6;
  int i = blockIdx.x * 256 + tid;
  int v = (i < N_NODES) ? cnt[i] : 0;
  int x = v;
#pragma unroll
  for (int d = 1; d < 64; d <<= 1) {
    int t = __shfl_up(x, d, 64);
    if (lane >= d) x += t;
  }
  if (lane == 63) wpart[wid] = x;
  __syncthreads();
  if (tid == 0) {
    int s = 0;
#pragma unroll
    for (int w = 0; w < 4; ++w) { int t = wpart[w]; wpart[w] = s; s += t; }
    __hip_atomic_store(&bsum[blockIdx.x], s, __ATOMIC_RELEASE,
                       __HIP_MEMORY_SCOPE_AGENT);
    int d = __hip_atomic_fetch_add(done, 1, __ATOMIC_ACQ_REL,
                                   __HIP_MEMORY_SCOPE_AGENT);
    lastf = (d == NB1 - 1);
  }
  __syncthreads();
  if (i < N_NODES) excl[i] = wpart[wid] + x - v;
  if (lastf) {                               // block-uniform branch
    int bv = (tid < NB1)
                 ? __hip_atomic_load(&bsum[tid], __ATOMIC_ACQUIRE,
                                     __HIP_MEMORY_SCOPE_AGENT)
                 : 0;
    sd[tid] = bv;
    __syncthreads();
    for (int d = 1; d < 256; d <<= 1) {
      int t = (tid >= d) ? sd[tid - d] : 0;
      __syncthreads();
      sd[tid] += t;
      __syncthreads();
    }
    if (tid < NB1) boff[tid] = sd[tid] - bv;
  }
}

// scatter: global slot = excl[d] + boff[d>>8] + (cnt[d]-- - 1). cnt holds the
// degree from the hist and is consumed as a descending cursor (neighbor order
// is an arbitrary permutation -> only fp32 reassociation noise downstream).
__global__ void k_scatter(const int* __restrict__ src, const int* __restrict__ dst,
                          const int* __restrict__ excl, const int* __restrict__ boff,
                          int* __restrict__ cnt, int* __restrict__ csr) {
  int i = blockIdx.x * blockDim.x + threadIdx.x;
  if (i < N_EDGES) {
    int d = dst[i];
    int r = atomicAdd(&cnt[d], -1);          // deg .. 1
    csr[excl[d] + boff[d >> 8] + r - 1] = src[i];
  }
}

// ---- aggregation: WAVE per node, 4 edge-slots x 16 feature-lanes, fp8 ------
__global__ __launch_bounds__(256) void k_agg_ep(
    const uint2* __restrict__ feat2, const unsigned int* __restrict__ epsw,
    const float* __restrict__ geps_p, const int* __restrict__ excl,
    const int* __restrict__ boff, const int* __restrict__ csr,
    uint4* __restrict__ agg4) {
  int wave = (blockIdx.x * blockDim.x + threadIdx.x) >> 6;   // node; grid exact
  int lane = threadIdx.x & 63;
  int li = lane & 15, es = lane >> 4;
  if (wave >= N_NODES) return;
  int n = wave;
  float ge = 1.0f + geps_p[0];
  int wsel = li >> 2, bsh = (li & 3) * 8;

  int off_n = excl[n] + boff[n >> 8];
  int e1 = (n == N_NODES - 1) ? N_EDGES : excl[n + 1] + boff[(n + 1) >> 8];

  // prefetch self row (used after reduction by lanes 0..15)
  uint2 sf = feat2[n * 16 + li];
  unsigned int swd = epsw[n * 4 + wsel];

  float af0 = 0.f, af1 = 0.f, af2 = 0.f, af3 = 0.f;
  float af4 = 0.f, af5 = 0.f, af6 = 0.f, af7 = 0.f;
  unsigned int accLo = 0, accHi = 0;

  int e = off_n + es;
  for (; e + 4 < e1; e += 8) {               // slots stride 4, unroll 2
    int s0 = csr[e], s1 = csr[e + 4];
    uint2 f0 = feat2[s0 * 16 + li];
    uint2 f1 = feat2[s1 * 16 + li];
    unsigned int w0 = epsw[s0 * 4 + wsel];
    unsigned int w1 = epsw[s1 * 4 + wsel];
    f8acc(f0.x, af0, af1, af2, af3);  f8acc(f0.y, af4, af5, af6, af7);
    f8acc(f1.x, af0, af1, af2, af3);  f8acc(f1.y, af4, af5, af6, af7);
    unsigned int B0 = (w0 >> bsh) & 0xFFu;
    unsigned int B1 = (w1 >> bsh) & 0xFFu;
    unsigned int r0 = B0 | (B0 << 8);  r0 |= r0 << 16;
    unsigned int r1 = B1 | (B1 << 8);  r1 |= r1 << 16;
    accLo += spreadLo(r0) + spreadLo(r1);
    accHi += spreadHi(r0) + spreadHi(r1);
  }
  if (e < e1) {
    int s0 = csr[e];
    uint2 f0 = feat2[s0 * 16 + li];
    unsigned int w0 = epsw[s0 * 4 + wsel];
    f8acc(f0.x, af0, af1, af2, af3);  f8acc(f0.y, af4, af5, af6, af7);
    unsigned int B0 = (w0 >> bsh) & 0xFFu;
    unsigned int r0 = B0 | (B0 << 8);  r0 |= r0 << 16;
    accLo += spreadLo(r0);
    accHi += spreadHi(r0);
  }

  // cross-slot reduction (lanes differing in bits 4,5). Packed-byte adds are
  // overflow-safe: per-byte totals <= degree << 255.
#pragma unroll
  for (int d = 16; d < 64; d <<= 1) {
    af0 += __shfl_xor(af0, d, 64);  af1 += __shfl_xor(af1, d, 64);
    af2 += __shfl_xor(af2, d, 64);  af3 += __shfl_xor(af3, d, 64);
    af4 += __shfl_xor(af4, d, 64);  af5 += __shfl_xor(af5, d, 64);
    af6 += __shfl_xor(af6, d, 64);  af7 += __shfl_xor(af7, d, 64);
    accLo += __shfl_xor((int)accLo, d, 64);
    accHi += __shfl_xor((int)accHi, d, 64);
  }

  if (es == 0) {
    // self term (fp8-rounded features, weight ge)
    f32x2 s0 = __builtin_amdgcn_cvt_pk_f32_fp8(sf.x, false);
    f32x2 s1 = __builtin_amdgcn_cvt_pk_f32_fp8(sf.x, true);
    f32x2 s2 = __builtin_amdgcn_cvt_pk_f32_fp8(sf.y, false);
    f32x2 s3 = __builtin_amdgcn_cvt_pk_f32_fp8(sf.y, true);
    af0 += ge * s0.x;  af1 += ge * s0.y;
    af2 += ge * s1.x;  af3 += ge * s1.y;
    af4 += ge * s2.x;  af5 += ge * s2.y;
    af6 += ge * s3.x;  af7 += ge * s3.y;
    unsigned int Bself = (swd >> bsh) & 0xFFu;
    float ev0 = ge * (float)(Bself & 1u)        + (float)(accLo & 0xFFu);
    float ev1 = ge * (float)((Bself >> 1) & 1u) + (float)((accLo >> 8) & 0xFFu);
    float ev2 = ge * (float)((Bself >> 2) & 1u) + (float)((accLo >> 16) & 0xFFu);
    float ev3 = ge * (float)((Bself >> 3) & 1u) + (float)((accLo >> 24) & 0xFFu);
    float ev4 = ge * (float)((Bself >> 4) & 1u) + (float)(accHi & 0xFFu);
    float ev5 = ge * (float)((Bself >> 5) & 1u) + (float)((accHi >> 8) & 0xFFu);
    float ev6 = ge * (float)((Bself >> 6) & 1u) + (float)((accHi >> 16) & 0xFFu);
    float ev7 = ge * (float)((Bself >> 7) & 1u) + (float)((accHi >> 24) & 0xFFu);

    uint4 oXh, oEp;
    oXh.x = pack2(af0, af1); oXh.y = pack2(af2, af3);
    oXh.z = pack2(af4, af5); oXh.w = pack2(af6, af7);
    oEp.x = pack2(ev0, ev1); oEp.y = pack2(ev2, ev3);
    oEp.z = pack2(ev4, ev5); oEp.w = pack2(ev6, ev7);
    agg4[n * 32 + li]      = oXh;   // features 8li..8li+7
    agg4[n * 32 + 16 + li] = oEp;   // eps features 128+8li..+7
  }
}

// ---- MFMA GEMM: 256 blocks x 512 threads (8 waves = 8 col-tiles). A tile
//      (16 nodes x 256 feats, 8KB) staged ONCE per block into padded LDS
//      (kills the 4x redundant per-wave global reads of the previous version)
//      with double-buffer + register prefetch of tile t+256. Epilogue:
//      fire-and-forget atomicAdd into sums[512] (131K atomics total). -------
__global__ __launch_bounds__(512) void k_gemm(const uint4* __restrict__ agg4,
    const unsigned short* __restrict__ Wp, const float* __restrict__ b,
    float* __restrict__ sums) {
  // LDS tile: 16 rows x 33 uint4 (528B row stride -> 2-way bank alias = free)
  __shared__ uint4 lds[2][544];
  int tid = threadIdx.x;
  int lane = tid & 63;
  int w = tid >> 6;            // wave = output col-tile i2 (0..7)
  int col = lane & 15;
  int quad = lane >> 4;

  const bf16x8* wp8 = (const bf16x8*)Wp;
  bf16x8 Bsh[4], Bep;
  float bias = b[w * 16 + col];
#pragma unroll
  for (int kb = 0; kb < 4; ++kb)
    Bsh[kb] = wp8[((w * 5 + kb) * 4 + quad) * 16 + col];
  Bep = wp8[((w * 5 + 4) * 4 + quad) * 16 + col];

  // staging map: thread stages padded slot p1=tid; tid<16 also stage 512+tid.
  int p1 = tid, row1 = p1 / 33, c1 = p1 - row1 * 33;
  int p2 = 512 + tid, row2 = p2 / 33, c2 = p2 - row2 * 33;
  bool v1 = (c1 < 32);
  bool v2 = (tid < 16) && (c2 < 32);

  f32x4 psum[4];
#pragma unroll
  for (int s = 0; s < 4; ++s) psum[s] = (f32x4){0.f, 0.f, 0.f, 0.f};

  // prologue: stage first tile into buf 0
  {
    int t0 = blockIdx.x;
    if (v1) lds[0][p1] = agg4[t0 * 512 + row1 * 32 + c1];
    if (v2) lds[0][p2] = agg4[t0 * 512 + row2 * 32 + c2];
  }
  int cur = 0;
  for (int t = blockIdx.x; t < NTILES; t += GEMM_BLOCKS) {
    int t2 = t + GEMM_BLOCKS;
    if (t2 >= NTILES) t2 = t;                // dead prefetch, never read
    uint4 r1, r2;
    if (v1) r1 = agg4[t2 * 512 + row1 * 32 + c1];
    if (v2) r2 = agg4[t2 * 512 + row2 * 32 + c2];

    __syncthreads();                         // lds[cur] staged; prior reads done

    const uint4* base = &lds[cur][col * 33];
    bf16x8 Ash[4];
#pragma unroll
    for (int kb = 0; kb < 4; ++kb)
      Ash[kb] = *(const bf16x8*)(base + kb * 4 + quad);
    f32x4 csh = (f32x4){0.f, 0.f, 0.f, 0.f};
#pragma unroll
    for (int kb = 0; kb < 4; ++kb)
      csh = __builtin_amdgcn_mfma_f32_16x16x32_bf16(Ash[kb], Bsh[kb], csh, 0, 0, 0);
#pragma unroll
    for (int s = 0; s < 4; ++s) {
      bf16x8 Aep = *(const bf16x8*)(base + 16 + s * 4 + quad);
      f32x4 c = __builtin_amdgcn_mfma_f32_16x16x32_bf16(Aep, Bep, csh, 0, 0, 0);
#pragma unroll
      for (int r = 0; r < 4; ++r)
        psum[s][r] += fmaxf(c[r] + bias, 0.f);
    }

    if (v1) lds[cur ^ 1][p1] = r1;           // stage next tile
    if (v2) lds[cur ^ 1][p2] = r2;
    cur ^= 1;
  }

#pragma unroll
  for (int s = 0; s < 4; ++s) {
    float v = psum[s][0] + psum[s][1] + psum[s][2] + psum[s][3];
    v += __shfl_xor(v, 16, 64);
    v += __shfl_xor(v, 32, 64);
    if (quad == 0)
      atomicAdd(&sums[s * 128 + w * 16 + col], v);
  }
}

// ---- broadcast output (mean+relu inline); eps already written by k_pack ----
__global__ void k_out(const float* __restrict__ sums, float* __restrict__ out) {
  int i = blockIdx.x * 256 + threadIdx.x;     // < 6.4M exact
  int o4 = i & 31;
  unsigned int sn = (unsigned int)i >> 5;     // s*N + node, < 200000
  unsigned int s = sn / (unsigned int)N_NODES;  // constant divisor -> magic mul
  float4 sv = ((const float4*)sums)[s * 32 + o4];
  float4 ov;
  ov.x = fmaxf(sv.x * INV_N, 0.f);
  ov.y = fmaxf(sv.y * INV_N, 0.f);
  ov.z = fmaxf(sv.z * INV_N, 0.f);
  ov.w = fmaxf(sv.w * INV_N, 0.f);
  ((float4*)out)[i] = ov;
}

extern "C" void kernel_launch(void* const* d_in, const int* in_sizes, int n_in,
                              void* d_out, int out_size, void* d_ws, size_t ws_size,
                              hipStream_t stream) {
  const float* X    = (const float*)d_in[0];
  const float* h    = (const float*)d_in[1];
  const float* eps  = (const float*)d_in[2];
  const float* W    = (const float*)d_in[3];
  const float* b    = (const float*)d_in[4];
  const float* geps = (const float*)d_in[5];
  const int*   src  = (const int*)d_in[6];
  const int*   dst  = (const int*)d_in[7];
  float* out = (float*)d_out;

  char* w = (char*)d_ws;
  unsigned int*  featF8 = (unsigned int*)w;  w += (size_t)N_NODES * 32 * 4;   // 6.4 MB
  unsigned int*  epsb   = (unsigned int*)w;  w += (size_t)N_NODES * 4 * 4;    // 0.8 MB
  unsigned int*  agg_u  = (unsigned int*)w;  w += (size_t)N_NODES * 128 * 4;  // 25.6 MB
  int*   excl     = (int*)w;   w += (size_t)(N_NODES + 16) * 4;
  int*   cnt      = (int*)w;   w += (size_t)N_NODES * 4;
  int*   csr      = (int*)w;   w += (size_t)N_EDGES * 4;
  int*   bsum     = (int*)w;   w += 256 * 4;
  int*   boff     = (int*)w;   w += 256 * 4;
  unsigned short* Wp = (unsigned short*)w; w += (size_t)20480 * 2;            // 40 KB
  float* sums     = (float*)w; w += 512 * 4;
  int*   done     = (int*)w;   w += 64;

  int eb = (N_EDGES + 255) / 256;
  hipMemsetAsync(cnt, 0, (size_t)N_NODES * 4, stream);
  k_pack<<<PB_TOT, 256, 0, stream>>>(X, h, eps, W, dst, featF8, epsb, cnt, Wp,
                                     out + EPS_OFF, sums, done);
  k_scan1<<<NB1, 256, 0, stream>>>(cnt, excl, bsum, boff, &done[0]);
  k_scatter<<<eb, 256, 0, stream>>>(src, dst, excl, boff, cnt, csr);

  k_agg_ep<<<(N_NODES * 64) / 256, 256, 0, stream>>>((const uint2*)featF8, epsb,
                                                     geps, excl, boff, csr,
                                                     (uint4*)agg_u);

  k_gemm<<<GEMM_BLOCKS, 512, 0, stream>>>((const uint4*)agg_u, Wp, b, sums);

  k_out<<<OUTB_F4 / 256, 256, 0, stream>>>(sums, out);
}